// Round 5
// baseline (411.890 us; speedup 1.0000x reference)
//
#include <hip/hip_runtime.h>

// BasalGanglia fused kernel (MI355X / gfx950).
// R10: two-batch-half software pipeline (phases offset by one segment).
// Evidence: R6(4bar)/R7(35%occ)/R9(3bar,LDS-diet) all pinned at 316-318us ->
// wall 13.4k cyc/iter vs ~5k busy => dependency-latency-bound at 2 waves/SIMD.
// The two batch halves (rows 0-15 / 16-31) are fully independent (all loop LDS
// state is row-partitioned; acc[j][mf] already per-half). Pipeline them one
// phase apart so every segment mixes independent MFMA/VALU/LDS chains in-wave:
//   seg0: A(h0,g)        | C(h1,g-1) | D(h0,g-1)
//   seg1: B(h0,g) A(h1,g)| D(h1,g-1)
//   seg2: C(h0,g)        | B(h1,g)
// Same 3 barriers/group, same work, same registers. Hazard matrix verified:
// every within-half RAW/WAR (vstn, xgpe dbuf, hxf, gates, vgpis) crosses >=1
// barrier; halves share no rows. Keeps R9's wins (acc-carry, permuted whh,
// lstmc pack, 672KB WRITE = no spill).

typedef _Float16 f16_t;
typedef _Float16 f16x8 __attribute__((ext_vector_type(8)));
typedef _Float16 f16x4 __attribute__((ext_vector_type(4)));
typedef float floatx4 __attribute__((ext_vector_type(4)));
typedef float floatx2 __attribute__((ext_vector_type(2)));

#define BTOT 8192
#define BM   32
#define NTHR 512
#define NBLK 256
#define VSTR 328   // f16 stride; dword-stride 164 -> uniform 8-lane bank groups (min)
#define XST  32    // xgpe/hxf row stride (f16), k-pad zeroed

template<int N> struct IC { static constexpr int v = N; };

struct Params {
  const float *stimulus, *deltavf, *hx0, *cx0;
  const float *w_vf0, *b_vf0, *w_vf1, *b_vf1, *w_vf2, *b_vf2, *w_vf3, *b_vf3;
  const float *w_jd1, *b_jd1, *w_jd2, *b_jd2, *w_kd1, *b_kd1, *w_kd2, *b_kd2;
  const float *w_sg, *b_sg, *w_gs, *b_gs, *w_glat, *b_glat, *w_slat, *b_slat;
  const float *w_d1gpi, *b_d1gpi, *w_stngpi, *b_stngpi;
  const float *w_ih, *b_ih, *w_hh, *b_hh;
  float* out;
};

struct __align__(16) Smem {
  f16_t vstn[BM * VSTR];        // 20992 B
  f16_t xgpe[2][BM * XST];      // 4096 (double buffer)
  f16_t hxf[BM * XST];          // 2048
  f16_t wB2[21 * 512];          // 21504: t<19 gs-frag, t=19/20 glat-frag
  f16_t wsp[10 * 512];          // 10240: stngpi frags
  f16_t whh[5 * 512];           // 5120: w_hh gate frags (row-permuted: r'=4j+g)
  union { float h1f[BM * 128]; float scr[3200]; float gates[BM * 80]; } u; // 16384
  float h0f[BM * 64];           // 8192
  float V_D2f[BM * 20];         // 2560
  float lstmc[20][12];          // 960: [j][bihh(4) | wih0(4) | wih1(4)]
  float bsumS[304];             // b_slat+b_gs, pad->0
  float bsg[20];                // b_sg+b_glat
  float DPs[BM * 2], vgpis[BM * 2], lamS[BM];
};                              // ~94 KB -> 1 block/CU

__device__ __forceinline__ float rcp_f(float x) { return __builtin_amdgcn_rcpf(x); }
__device__ __forceinline__ float sigm_fast(float x) { return rcp_f(1.f + __expf(-x)); }
__device__ __forceinline__ float tanh_fast(float x) { return 1.f - 2.f * rcp_f(1.f + __expf(2.f * x)); }

// 8 f32 weights row[k0..k0+7] -> f16x8, zero for k>=kmax or !valid (4-granular).
__device__ __forceinline__ f16x8 ldfrag(const float* row, int k0, int kmax, bool valid) {
  float4 z = make_float4(0.f, 0.f, 0.f, 0.f);
  int nv = valid ? (kmax - k0) : 0;
  float4 f0 = (nv >= 4) ? *(const float4*)(row + k0) : z;
  float4 f1 = (nv >= 8) ? *(const float4*)(row + k0 + 4) : z;
  f16x8 r;
  r[0] = (f16_t)f0.x; r[1] = (f16_t)f0.y; r[2] = (f16_t)f0.z; r[3] = (f16_t)f0.w;
  r[4] = (f16_t)f1.x; r[5] = (f16_t)f1.y; r[6] = (f16_t)f1.z; r[7] = (f16_t)f1.w;
  return r;
}

__global__ __launch_bounds__(NTHR, 2) void bg_main(Params P) {
  __shared__ Smem S;
  const int tid  = threadIdx.x;
  const int lane = tid & 63;
  const int wv   = tid >> 6;
  const int q    = lane >> 4;
  const int cl   = lane & 15;
  const int row0 = blockIdx.x * BM;
  const floatx4 zf = {0.f, 0.f, 0.f, 0.f};

  // ================= init + LDS weight-frag staging =================
  if (tid < BM) S.lamS[tid] = sigm_fast(P.deltavf[row0 + tid]);
  for (int i = tid; i < BM * 2; i += NTHR) S.vgpis[i] = 0.f;
  for (int i = tid; i < 2 * BM * XST; i += NTHR) ((f16_t*)S.xgpe)[i] = (f16_t)0.f;
  for (int i = tid; i < BM * XST; i += NTHR) {
    int m = i >> 5, j = i & 31;
    S.hxf[i] = (j < 20) ? (f16_t)P.hx0[row0 * 20 + m * 20 + j] : (f16_t)0.f;
  }
  for (int i = tid; i < BM * VSTR; i += NTHR) S.vstn[i] = (f16_t)0.f;
  for (int i = tid; i < 21 * 512; i += NTHR) {        // gs / glat frags
    int t = i >> 9, l = (i >> 3) & 63, jj = i & 7;
    int c2 = l & 15, k = ((l >> 4) << 3) + jj;
    float v = 0.f;
    if (t < 19) { int n = t * 16 + c2; if (n < 300 && k < 20) v = P.w_gs[n * 20 + k]; }
    else        { int g = (t - 19) * 16 + c2; if (g < 20 && k < 20) v = P.w_glat[g * 20 + k]; }
    S.wB2[i] = (f16_t)v;
  }
  for (int i = tid; i < 10 * 512; i += NTHR) {        // stngpi frags
    int c = i >> 9, l = (i >> 3) & 63, jj = i & 7;
    int p = l & 15, k = c * 32 + ((l >> 4) << 3) + jj;
    float v = (p < 2 && k < 300) ? P.w_stngpi[p * 300 + k] : 0.f;
    S.wsp[i] = (f16_t)v;
  }
  for (int i = tid; i < 5 * 512; i += NTHR) {         // w_hh gate frags, PERMUTED
    int t = i >> 9, l = (i >> 3) & 63, jj = i & 7;
    int c2 = l & 15, k = ((l >> 4) << 3) + jj;
    // tile-row c2 -> permuted gate-row r' = 16t+c2 = 4j+g -> orig row g*20+j
    int orig = (c2 & 3) * 20 + 4 * t + (c2 >> 2);
    S.whh[i] = (f16_t)((k < 20) ? P.w_hh[orig * 20 + k] : 0.f);
  }
  for (int i = tid; i < 240; i += NTHR) {             // LSTM consts [j][12]
    int j = i / 12, c = i - j * 12;
    float v;
    if (c < 4)      v = P.b_ih[c * 20 + j] + P.b_hh[c * 20 + j];
    else if (c < 8) v = P.w_ih[((c - 4) * 20 + j) * 2 + 0];
    else            v = P.w_ih[((c - 8) * 20 + j) * 2 + 1];
    S.lstmc[j][c] = v;
  }
  for (int i = tid; i < 304; i += NTHR) S.bsumS[i] = (i < 300) ? (P.b_slat[i] + P.b_gs[i]) : 0.f;
  for (int i = tid; i < 20; i += NTHR)  S.bsg[i] = P.b_sg[i] + P.b_glat[i];

  { // h0 = relu(stim @ w_vf0^T + b)
    int o = tid & 63, mb = (tid >> 6) * 4;
    const float4* wr = (const float4*)(P.w_vf0 + o * 300);
    float bias = P.b_vf0[o], a[4];
#pragma unroll
    for (int u = 0; u < 4; ++u) a[u] = bias;
    for (int kq = 0; kq < 75; ++kq) {
      float4 w = wr[kq];
#pragma unroll
      for (int u = 0; u < 4; ++u) {
        float4 v = *(const float4*)(P.stimulus + (size_t)(row0 + mb + u) * 300 + kq * 4);
        a[u] = fmaf(v.x, w.x, a[u]); a[u] = fmaf(v.y, w.y, a[u]);
        a[u] = fmaf(v.z, w.z, a[u]); a[u] = fmaf(v.w, w.w, a[u]);
      }
    }
#pragma unroll
    for (int u = 0; u < 4; ++u) S.h0f[(mb + u) * 64 + o] = fmaxf(a[u], 0.f);
  }
  __syncthreads();
  { // h1
    int o = tid & 127, mb = (tid >> 7) * 8;
    const float* wr = P.w_vf1 + o * 64;
    float bias = P.b_vf1[o], a[8];
#pragma unroll
    for (int u = 0; u < 8; ++u) a[u] = bias;
    for (int k = 0; k < 64; ++k) {
      float w = wr[k];
#pragma unroll
      for (int u = 0; u < 8; ++u) a[u] = fmaf(S.h0f[(mb + u) * 64 + k], w, a[u]);
    }
#pragma unroll
    for (int u = 0; u < 8; ++u) S.u.h1f[(mb + u) * 128 + o] = fmaxf(a[u], 0.f);
  }
  __syncthreads();
  { // h2 -> h0f
    int o = tid & 63, mb = (tid >> 6) * 4;
    const float* wr = P.w_vf2 + o * 128;
    float bias = P.b_vf2[o], a[4];
#pragma unroll
    for (int u = 0; u < 4; ++u) a[u] = bias;
    for (int k = 0; k < 128; ++k) {
      float w = wr[k];
#pragma unroll
      for (int u = 0; u < 4; ++u) a[u] = fmaf(S.u.h1f[(mb + u) * 128 + k], w, a[u]);
    }
#pragma unroll
    for (int u = 0; u < 4; ++u) S.h0f[(mb + u) * 64 + o] = fmaxf(a[u], 0.f);
  }
  __syncthreads();
  { // drives -> scr[0:2560); vt output
    int oid = tid & 127, mb = (tid >> 7) * 8;
    if (oid < 80) {
      int which = oid / 20, o = oid - which * 20;
      const float *wp, *bp;
      if (which == 0)      { wp = P.w_jd1; bp = P.b_jd1; }
      else if (which == 1) { wp = P.w_jd2; bp = P.b_jd2; }
      else if (which == 2) { wp = P.w_kd1; bp = P.b_kd1; }
      else                 { wp = P.w_kd2; bp = P.b_kd2; }
      float bias = bp[o], a[8];
#pragma unroll
      for (int u = 0; u < 8; ++u) a[u] = bias;
      for (int kq = 0; kq < 75; ++kq) {
        float4 w = *(const float4*)(wp + o * 300 + kq * 4);
#pragma unroll
        for (int u = 0; u < 8; ++u) {
          float4 v = *(const float4*)(P.stimulus + (size_t)(row0 + mb + u) * 300 + kq * 4);
          a[u] = fmaf(v.x, w.x, a[u]); a[u] = fmaf(v.y, w.y, a[u]);
          a[u] = fmaf(v.z, w.z, a[u]); a[u] = fmaf(v.w, w.w, a[u]);
        }
      }
#pragma unroll
      for (int u = 0; u < 8; ++u) S.u.scr[which * 640 + (mb + u) * 20 + o] = a[u];
    }
    if (tid < BM) {
      float a = P.b_vf3[0];
      for (int k = 0; k < 64; ++k) a = fmaf(S.h0f[tid * 64 + k], P.w_vf3[k], a);
      P.out[(size_t)BTOT * 20 + row0 + tid] = tanh_fast(a);
    }
  }
  __syncthreads();
  for (int i = tid; i < BM * 20; i += NTHR) { // FF -> V_D1 scr[2560:), V_D2f
    int m = i / 20;
    float j1 = S.u.scr[i],        j2 = S.u.scr[640 + i];
    float k1 = S.u.scr[1280 + i], k2 = S.u.scr[1920 + i];
    float L = S.lamS[m], v1 = 0.f, v2 = 0.f;
    for (int s = 0; s < 20; ++s) {
      v1 = sigm_fast(L * (j1 * (1.f - v1) + (1.f - k1) * v1));
      v2 = sigm_fast(L * (j2 * (1.f - v2) + (1.f - k2) * v2));
    }
    S.u.scr[2560 + i] = v1;
    S.V_D2f[i] = v2;
  }
  __syncthreads();
  if (tid < BM * 2) { // V_GPi_DP
    int m = tid >> 1, p2 = tid & 1;
    float a = P.b_d1gpi[p2];
    for (int o = 0; o < 20; ++o) a = fmaf(S.u.scr[2560 + m * 20 + o], P.w_d1gpi[p2 * 20 + o], a);
    S.DPs[tid] = a;
  }
  __syncthreads();

  // ================= register-resident slat/sg A-frags (R6 map) =================
  // slot j: tile t = wv + 8*j; t<19 slat, t=19/20 sg (waves 3,4), t>=21 dead.
  f16x8 Ws[3][10];
#pragma unroll
  for (int j = 0; j < 3; ++j) {
    int t = wv + 8 * j;
    if (t < 19) {
      int n = t * 16 + cl;
#pragma unroll
      for (int c = 0; c < 10; ++c)
        Ws[j][c] = ldfrag(P.w_slat + (size_t)(n < 300 ? n : 0) * 300, c * 32 + q * 8, 300, n < 300);
    } else if (t < 21) {
      int g = (t - 19) * 16 + cl;
#pragma unroll
      for (int c = 0; c < 10; ++c)
        Ws[j][c] = ldfrag(P.w_sg + (size_t)(g < 20 ? g : 0) * 300, c * 32 + q * 8, 300, g < 20);
    } else {
      f16x8 z;
#pragma unroll
      for (int e = 0; e < 8; ++e) z[e] = (f16_t)0.f;
#pragma unroll
      for (int c = 0; c < 10; ++c) Ws[j][c] = z;
    }
  }
  const float lam0 = S.lamS[cl], lam1 = S.lamS[cl + 16];
  const float bstn0 = P.b_stngpi[0], bstn1 = P.b_stngpi[1];
  const bool isSgW = (wv == 3 || wv == 4);
  // LSTM: thread tid<320 owns elem (m0, j0) of EACH half (rows m0 and 16+m0).
  const bool lown = (tid < BM * 20 / 2);      // 320
  const int  m0 = lown ? tid / 20 : 0;
  const int  j0 = tid - m0 * 20;
  float cxr0_ = lown ? P.cx0[(size_t)(row0 + m0) * 20 + j0] : 0.f;
  float cxr1_ = lown ? P.cx0[(size_t)(row0 + 16 + m0) * 20 + j0] : 0.f;
  float hxr0_ = 0.f, hxr1_ = 0.f;

  // acc carries 2*xstn across iterations (slat slots); [slot][half].
  floatx4 acc[3][2];
#pragma unroll
  for (int j = 0; j < 3; ++j) { acc[j][0] = zf; acc[j][1] = zf; }

  // ---------------- phase lambdas (H = batch half, compile-time) ----------------
  auto phaseA = [&](auto Hc, int it) {
    constexpr int H = decltype(Hc)::v;
    const int po = it & 1, pn = po ^ 1;
    const int br = H * 16 + cl;
    if (isSgW) acc[2][H] = zf;               // sg slot fresh per iter
    __builtin_amdgcn_s_setprio(1);
#pragma unroll
    for (int c = 0; c < 10; ++c) {
      f16x8 b0 = *(const f16x8*)&S.vstn[br * VSTR + c * 32 + q * 8];
#pragma unroll
      for (int j = 0; j < 3; ++j) {
        if (wv + 8 * j < 21)
          acc[j][H] = __builtin_amdgcn_mfma_f32_16x16x32_f16(Ws[j][c], b0, acc[j][H], 0, 0, 0);
      }
    }
    __builtin_amdgcn_s_setprio(0);
    if (isSgW) {
      f16x8 Wg = *(const f16x8*)&S.wB2[(wv + 16) * 512 + lane * 8];
      f16x8 g0 = *(const f16x8*)&S.xgpe[po][br * XST + q * 8];
      acc[2][H] = __builtin_amdgcn_mfma_f32_16x16x32_f16(Wg, g0, acc[2][H], 0, 0, 0);
      int g0i = (wv - 3) * 16 + q * 4;
      if (g0i < 20) {
        floatx4 bg4 = *(const floatx4*)&S.bsg[g0i];
        floatx4 vd4 = *(const floatx4*)&S.V_D2f[br * 20 + g0i];
        f16x4 pk;
#pragma unroll
        for (int r = 0; r < 4; ++r) pk[r] = (f16_t)(acc[2][H][r] + bg4[r] - vd4[r]);
        *(f16x4*)&S.xgpe[pn][br * XST + g0i] = pk;
      }
    }
  };

  auto phaseB = [&](auto Hc, int it) {
    constexpr int H = decltype(Hc)::v;
    const int pn = (it & 1) ^ 1;
    const int br = H * 16 + cl;
    f16x8 x0 = *(const f16x8*)&S.xgpe[pn][br * XST + q * 8];
    if (wv < 5) { // hh-gates (permuted rows): gates[batch][4j+g]
      f16x8 Wh = *(const f16x8*)&S.whh[wv * 512 + lane * 8];
      f16x8 hv = *(const f16x8*)&S.hxf[br * XST + q * 8];
      floatx4 gA = __builtin_amdgcn_mfma_f32_16x16x32_f16(Wh, hv, zf, 0, 0, 0);
      *(floatx4*)&S.u.gates[br * 80 + wv * 16 + q * 4] = gA;
    }
#pragma unroll
    for (int j = 0; j < 3; ++j) {
      int t = wv + 8 * j;
      if (t < 19) {
        f16x8 Wg = *(const f16x8*)&S.wB2[t * 512 + lane * 8];
        acc[j][H] = __builtin_amdgcn_mfma_f32_16x16x32_f16(Wg, x0, acc[j][H], 0, 0, 0);
      }
    }
    const float lm = H ? lam1 : lam0;
#pragma unroll
    for (int j = 0; j < 3; ++j) {
      int t = wv + 8 * j;
      if (t < 19) {
        int n0 = t * 16 + q * 4;
        if (!(t == 18 && q == 3)) {  // n0..n0+3 all < 300
          floatx4 bs4 = *(const floatx4*)&S.bsumS[n0];
          f16x4 pk;
#pragma unroll
          for (int r = 0; r < 4; ++r) {
            float tmp = acc[j][H][r] + bs4[r];      // = 2*xo + W.v + bs
            float xn  = tmp * (1.0f / 3.0f);        // new xstn
            acc[j][H][r] = tmp * (2.0f / 3.0f);     // carry 2*xn
            pk[r] = (f16_t)tanh_fast(lm * xn);
          }
          *(f16x4*)&S.vstn[br * VSTR + n0] = pk;
        }
      }
    }
  };

  auto phaseC = [&](auto Hc) {
    constexpr int H = decltype(Hc)::v;
    if (wv == 5) {
      const int br = H * 16 + cl;
      floatx4 ip0 = zf;
#pragma unroll
      for (int c = 0; c < 10; ++c) {
        f16x8 Wp = *(const f16x8*)&S.wsp[c * 512 + lane * 8];
        f16x8 b0 = *(const f16x8*)&S.vstn[br * VSTR + c * 32 + q * 8];
        ip0 = __builtin_amdgcn_mfma_f32_16x16x32_f16(Wp, b0, ip0, 0, 0, 0);
      }
      if (q == 0) {
        const float lm = H ? lam1 : lam0;
        floatx2 vg = *(const floatx2*)&S.vgpis[br * 2];
        floatx2 dp = *(const floatx2*)&S.DPs[br * 2];
        float ipa = lm * (ip0[0] + bstn0);
        float ipb = lm * (ip0[1] + bstn1);
        vg[0] = vg[0] + 0.1f * (-vg[0] - dp[0] + 2.f * ipa);
        vg[1] = vg[1] + 0.1f * (-vg[1] - dp[1] + 2.f * ipb);
        *(floatx2*)&S.vgpis[br * 2] = vg;
      }
    }
  };

  auto phaseD = [&](auto Hc, float& cxr, float& hxr) {
    constexpr int H = decltype(Hc)::v;
    if (lown) {
      const int br = H * 16 + m0;
      floatx4 g4 = *(const floatx4*)&S.u.gates[br * 80 + j0 * 4];
      floatx4 cb = *(const floatx4*)&S.lstmc[j0][0];
      floatx4 w0 = *(const floatx4*)&S.lstmc[j0][4];
      floatx4 w1 = *(const floatx4*)&S.lstmc[j0][8];
      floatx2 vg = *(const floatx2*)&S.vgpis[br * 2];
      float gi = g4[0] + cb[0] - w0[0] * vg[0] - w1[0] * vg[1];
      float gf = g4[1] + cb[1] - w0[1] * vg[0] - w1[1] * vg[1];
      float gg = g4[2] + cb[2] - w0[2] * vg[0] - w1[2] * vg[1];
      float go = g4[3] + cb[3] - w0[3] * vg[0] - w1[3] * vg[1];
      float cn = sigm_fast(gf) * cxr + sigm_fast(gi) * tanh_fast(gg);
      cxr = cn;
      hxr = sigm_fast(go) * tanh_fast(cn);
      S.hxf[br * XST + j0] = (f16_t)hxr;
    }
  };

  // ================= STN recurrence: 51 pipelined groups, 3 barriers each ====
  for (int g = 0; g <= 50; ++g) {
    const bool run = (g < 50), ran = (g > 0);
    // seg0: A(h0,g) | C(h1,g-1) | D(h0,g-1)
    if (run) phaseA(IC<0>{}, g);
    if (ran) phaseC(IC<1>{});
    if (ran) phaseD(IC<0>{}, cxr0_, hxr0_);
    __syncthreads();
    // seg1: B(h0,g), A(h1,g) | D(h1,g-1)
    if (run) { phaseB(IC<0>{}, g); phaseA(IC<1>{}, g); }
    if (ran) phaseD(IC<1>{}, cxr1_, hxr1_);
    __syncthreads();
    // seg2: C(h0,g) | B(h1,g)
    if (run) { phaseC(IC<0>{}); phaseB(IC<1>{}, g); }
    __syncthreads();
  }

  // ---- output hx from registers ----
  if (lown) {
    P.out[(size_t)(row0 + m0) * 20 + j0]      = hxr0_;
    P.out[(size_t)(row0 + 16 + m0) * 20 + j0] = hxr1_;
  }
}

extern "C" void kernel_launch(void* const* d_in, const int* in_sizes, int n_in,
                              void* d_out, int out_size, void* d_ws, size_t ws_size,
                              hipStream_t stream) {
  (void)in_sizes; (void)n_in; (void)out_size; (void)d_ws; (void)ws_size;
  Params P;
  P.stimulus = (const float*)d_in[0];
  P.deltavf  = (const float*)d_in[1];
  P.hx0 = (const float*)d_in[2];
  P.cx0 = (const float*)d_in[3];
  P.w_vf0 = (const float*)d_in[4];  P.b_vf0 = (const float*)d_in[5];
  P.w_vf1 = (const float*)d_in[6];  P.b_vf1 = (const float*)d_in[7];
  P.w_vf2 = (const float*)d_in[8];  P.b_vf2 = (const float*)d_in[9];
  P.w_vf3 = (const float*)d_in[10]; P.b_vf3 = (const float*)d_in[11];
  P.w_jd1 = (const float*)d_in[12]; P.b_jd1 = (const float*)d_in[13];
  P.w_jd2 = (const float*)d_in[14]; P.b_jd2 = (const float*)d_in[15];
  P.w_kd1 = (const float*)d_in[16]; P.b_kd1 = (const float*)d_in[17];
  P.w_kd2 = (const float*)d_in[18]; P.b_kd2 = (const float*)d_in[19];
  P.w_sg  = (const float*)d_in[20]; P.b_sg  = (const float*)d_in[21];
  P.w_gs  = (const float*)d_in[22]; P.b_gs  = (const float*)d_in[23];
  P.w_glat= (const float*)d_in[24]; P.b_glat= (const float*)d_in[25];
  P.w_slat= (const float*)d_in[26]; P.b_slat= (const float*)d_in[27];
  P.w_d1gpi  = (const float*)d_in[28]; P.b_d1gpi  = (const float*)d_in[29];
  P.w_stngpi = (const float*)d_in[30]; P.b_stngpi = (const float*)d_in[31];
  P.w_ih = (const float*)d_in[32]; P.b_ih = (const float*)d_in[33];
  P.w_hh = (const float*)d_in[34]; P.b_hh = (const float*)d_in[35];
  P.out  = (float*)d_out;
  bg_main<<<NBLK, NTHR, 0, stream>>>(P);
}